// Round 11
// baseline (70.327 us; speedup 1.0000x reference)
//
#include <hip/hip_runtime.h>
#include <stdint.h>

// MaxSimLoss: anchor [256,64,128] f32, pos/neg [256,512,128] f32 -> scalar f32.
// R10 post-mortem: coalescing falsified (DMA-staged == scattered-direct).
// Five structures all pin at ~4.07 TB/s with Occupancy ~20% (2 waves/SIMD):
// 108 arch + ~16 AGPR crosses the 128-reg quantum, halving waves/SIMD, so
// per-CU in-flight is stuck at 64 KB everywhere. R11: single variable vs R9 —
// __launch_bounds__(256,3): 170-reg cap (no spill, demand ~124) lets the
// allocator target 3 waves/SIMD = 12 waves/CU (+50% in-flight).

#define MARGIN_F 0.1f

typedef __attribute__((ext_vector_type(8))) short short8;   // 8 bf16
typedef __attribute__((ext_vector_type(4))) float floatx4;  // 4 f32 acc

// f32 -> bf16 round-to-nearest-even (inputs finite).
__device__ __forceinline__ unsigned short f2bf(float f) {
  union { float f; uint32_t u; } x; x.f = f;
  uint32_t u = x.u;
  return (unsigned short)((u + 0x7FFFu + ((u >> 16) & 1u)) >> 16);
}

__device__ __forceinline__ short8 pack8(float4 a, float4 b) {
  short8 r;
  r[0] = (short)f2bf(a.x); r[1] = (short)f2bf(a.y);
  r[2] = (short)f2bf(a.z); r[3] = (short)f2bf(a.w);
  r[4] = (short)f2bf(b.x); r[5] = (short)f2bf(b.y);
  r[6] = (short)f2bf(b.z); r[7] = (short)f2bf(b.w);
  return r;
}

__device__ __forceinline__ float sq4(float4 a) {
  return a.x * a.x + a.y * a.y + a.z * a.z + a.w * a.w;
}

// One block per (batch, side, s-half); 4 waves partition the 256-row s-half
// (64 rows each, 4 chunks of 16). Fragment pattern (verified R2/R3): lane
// holds row (lane&15), elements (lane>>4)*8 + k*32..+8 per k-slice; identical
// for A and B -> D = A.B^T with row(t) = (lane>>4)*4 + j, col(s) = lane&15.
__global__ __launch_bounds__(256, 3) void maxsim_kernel(
    const float* __restrict__ anchor, const float* __restrict__ pos,
    const float* __restrict__ neg, float* __restrict__ part) {
  __shared__ float sInvA[64];
  __shared__ float sPart[4][64];

  int bs2 = blockIdx.x;     // 0..1023 = ((b*2+side)*2+sh)
  int sh = bs2 & 1;         // s-half
  int bs = bs2 >> 1;        // (batch, side)
  int b = bs >> 1;
  int side = bs & 1;
  const float* base =
      (side ? neg : pos) + (size_t)b * 512 * 128 + (size_t)sh * 256 * 128;
  const float* abase = anchor + (size_t)b * 64 * 128;

  int tid = threadIdx.x;
  int lane = tid & 63;
  int wid = tid >> 6;  // 0..3
  int r = lane & 15;   // fragment row within subtile / accumulator col
  int g = lane >> 4;   // k-group (elements g*8 + k*32)

  const float* sbase = base + (size_t)wid * 64 * 128;

  // Issue chunk-0 s-loads FIRST so their latency hides under the anchor phase.
  float4 buf[2][8];  // fully unrolled chunk loop -> static indexing (rule #20)
  {
    const float* p = sbase + (size_t)r * 128 + g * 8;
#pragma unroll
    for (int k = 0; k < 4; ++k) {
      buf[0][2 * k] = *reinterpret_cast<const float4*>(p + k * 32);
      buf[0][2 * k + 1] = *reinterpret_cast<const float4*>(p + k * 32 + 4);
    }
  }

  // --- A: all 4 t-subtiles into registers, norms in-register. ---
  short8 aF[4][4];
#pragma unroll
  for (int tst = 0; tst < 4; ++tst) {
    const float* arow = abase + (size_t)(tst * 16 + r) * 128 + g * 8;
    float ssa[4];
#pragma unroll
    for (int k = 0; k < 4; ++k) {
      float4 v0 = *reinterpret_cast<const float4*>(arow + k * 32);
      float4 v1 = *reinterpret_cast<const float4*>(arow + k * 32 + 4);
      ssa[k] = sq4(v0) + sq4(v1);
      aF[tst][k] = pack8(v0, v1);
    }
    float ss = (ssa[0] + ssa[1]) + (ssa[2] + ssa[3]);  // tree, short chain
    ss += __shfl_xor(ss, 16);
    ss += __shfl_xor(ss, 32);
    if (g == 0) sInvA[tst * 16 + r] = 1.0f / fmaxf(sqrtf(ss), 1e-12f);
  }
  __syncthreads();  // sInvA ready; last sync until epilogue

  float rmax[4][4];
#pragma unroll
  for (int tst = 0; tst < 4; ++tst)
#pragma unroll
    for (int j = 0; j < 4; ++j) rmax[tst][j] = -1e30f;

#pragma unroll
  for (int i = 0; i < 4; ++i) {
    int cur = i & 1;
    if (i < 3) {
      const float* p = sbase + (size_t)((i + 1) * 16 + r) * 128 + g * 8;
#pragma unroll
      for (int k = 0; k < 4; ++k) {
        buf[cur ^ 1][2 * k] = *reinterpret_cast<const float4*>(p + k * 32);
        buf[cur ^ 1][2 * k + 1] =
            *reinterpret_cast<const float4*>(p + k * 32 + 4);
      }
    }
    // Row norm for this lane's loaded row (s = sh*256 + wid*64 + i*16 + r).
    float ss = ((sq4(buf[cur][0]) + sq4(buf[cur][1])) +
                (sq4(buf[cur][2]) + sq4(buf[cur][3]))) +
               ((sq4(buf[cur][4]) + sq4(buf[cur][5])) +
                (sq4(buf[cur][6]) + sq4(buf[cur][7])));
    ss += __shfl_xor(ss, 16);
    ss += __shfl_xor(ss, 32);
    float invb = 1.0f / fmaxf(sqrtf(ss), 1e-12f);

    short8 bF[4];
#pragma unroll
    for (int k = 0; k < 4; ++k)
      bF[k] = pack8(buf[cur][2 * k], buf[cur][2 * k + 1]);

    floatx4 acc[4] = {{0.f, 0.f, 0.f, 0.f},
                      {0.f, 0.f, 0.f, 0.f},
                      {0.f, 0.f, 0.f, 0.f},
                      {0.f, 0.f, 0.f, 0.f}};
#pragma unroll
    for (int k = 0; k < 4; ++k)
#pragma unroll
      for (int tst = 0; tst < 4; ++tst)
        acc[tst] = __builtin_amdgcn_mfma_f32_16x16x32_bf16(aF[tst][k], bF[k],
                                                           acc[tst], 0, 0, 0);
    // acc[tst][j]: row t = tst*16 + g*4 + j, col s-rel = lane&15.
    // invb for col r is this lane's own invb (it loaded row i*16 + r).
#pragma unroll
    for (int tst = 0; tst < 4; ++tst)
#pragma unroll
      for (int j = 0; j < 4; ++j)
        rmax[tst][j] = fmaxf(rmax[tst][j], acc[tst][j] * invb);
  }

  // Butterfly-max over cols (lane bits 0-3) -> per-t max over wave's s-range.
#pragma unroll
  for (int tst = 0; tst < 4; ++tst)
#pragma unroll
    for (int j = 0; j < 4; ++j) {
      float m = rmax[tst][j];
      m = fmaxf(m, __shfl_xor(m, 1));
      m = fmaxf(m, __shfl_xor(m, 2));
      m = fmaxf(m, __shfl_xor(m, 4));
      m = fmaxf(m, __shfl_xor(m, 8));
      rmax[tst][j] = m;  // t = tst*16 + g*4 + j, uniform over lane bits 0-3
    }
  if (r == 0) {
#pragma unroll
    for (int tst = 0; tst < 4; ++tst)
#pragma unroll
      for (int j = 0; j < 4; ++j)
        sPart[wid][tst * 16 + g * 4 + j] = rmax[tst][j];
  }
  __syncthreads();
  // Per-t partial max over this block's 256 s-rows, scaled by invA (positive,
  // commutes with the cross-block max done in the hinge stage).
  if (tid < 64) {
    float m = fmaxf(fmaxf(sPart[0][tid], sPart[1][tid]),
                    fmaxf(sPart[2][tid], sPart[3][tid]));
    part[(size_t)bs2 * 64 + tid] = m * sInvA[tid];
  }
}

// Stage 2: one 1-wave block per batch. part segments for batch b:
// [b*4+0]=pos/h0, [b*4+1]=pos/h1, [b*4+2]=neg/h0, [b*4+3]=neg/h1 (64 t each).
__global__ void hinge_batch_kernel(const float* __restrict__ part,
                                   float* __restrict__ hb) {
  int b = blockIdx.x;       // 0..255
  int t = threadIdx.x;      // 0..63
  const float* p = part + (size_t)b * 256;
  float pm = fmaxf(p[t], p[64 + t]);
  float nm = fmaxf(p[128 + t], p[192 + t]);
#pragma unroll
  for (int m = 1; m < 64; m <<= 1) {
    pm += __shfl_xor(pm, m);
    nm += __shfl_xor(nm, m);
  }
  if (t == 0)
    hb[b] = fmaxf(MARGIN_F + nm * (1.0f / 64.0f) - pm * (1.0f / 64.0f), 0.0f);
}

// Stage 3: mean over 256 batches.
__global__ void final_kernel(const float* __restrict__ hb,
                             float* __restrict__ out) {
  int tid = threadIdx.x;  // 0..255
  float h = hb[tid];
#pragma unroll
  for (int m = 1; m < 64; m <<= 1) h += __shfl_xor(h, m);
  __shared__ float sw[4];
  if ((tid & 63) == 0) sw[tid >> 6] = h;
  __syncthreads();
  if (tid == 0) out[0] = (sw[0] + sw[1] + sw[2] + sw[3]) * (1.0f / 256.0f);
}

extern "C" void kernel_launch(void* const* d_in, const int* in_sizes, int n_in,
                              void* d_out, int out_size, void* d_ws,
                              size_t ws_size, hipStream_t stream) {
  const float* anchor = (const float*)d_in[0];
  const float* pos = (const float*)d_in[1];
  const float* neg = (const float*)d_in[2];
  float* part = (float*)d_ws;               // 1024 x 64 floats = 256 KB
  float* hb = part + 1024 * 64;             // 256 floats
  maxsim_kernel<<<dim3(1024), dim3(256), 0, stream>>>(anchor, pos, neg, part);
  hinge_batch_kernel<<<dim3(256), dim3(64), 0, stream>>>(part, hb);
  final_kernel<<<dim3(1), dim3(256), 0, stream>>>(hb, (float*)d_out);
}

// Round 12
// 55.857 us; speedup vs baseline: 1.2591x; 1.2591x over previous
//
#include <hip/hip_runtime.h>
#include <stdint.h>

// MaxSimLoss: anchor [256,64,128] f32, pos/neg [256,512,128] f32 -> scalar f32.
// R11 post-mortem: launch_bounds occupancy forcing ALWAYS spills (3rd time).
// Cross-round delta R3 vs R9 shows ~3-6us per extra tail launch. All
// non-spilling variants sit at ~4 TB/s with depth-1 prefetch (8KB/wave in
// flight). R12: (a) depth-2 prefetch via buf[3] rotation -> 16KB/wave in
// flight (VGPR ~140 < 256 cap, no spill, and allows 3 waves/SIMD since
// launch_bounds is a minimum); (b) single-kernel fusion: last block (atomic
// counter) computes hinge+mean, eliminating both tail launches.

#define MARGIN_F 0.1f

typedef __attribute__((ext_vector_type(8))) short short8;   // 8 bf16
typedef __attribute__((ext_vector_type(4))) float floatx4;  // 4 f32 acc

// f32 -> bf16 round-to-nearest-even (inputs finite).
__device__ __forceinline__ unsigned short f2bf(float f) {
  union { float f; uint32_t u; } x; x.f = f;
  uint32_t u = x.u;
  return (unsigned short)((u + 0x7FFFu + ((u >> 16) & 1u)) >> 16);
}

__device__ __forceinline__ short8 pack8(float4 a, float4 b) {
  short8 r;
  r[0] = (short)f2bf(a.x); r[1] = (short)f2bf(a.y);
  r[2] = (short)f2bf(a.z); r[3] = (short)f2bf(a.w);
  r[4] = (short)f2bf(b.x); r[5] = (short)f2bf(b.y);
  r[6] = (short)f2bf(b.z); r[7] = (short)f2bf(b.w);
  return r;
}

__device__ __forceinline__ float sq4(float4 a) {
  return a.x * a.x + a.y * a.y + a.z * a.z + a.w * a.w;
}

// One block per (batch, side); 4 waves partition s (128 rows each, 8 chunks
// of 16). Fragment pattern (verified R2/R3): lane holds row (lane&15),
// elements (lane>>4)*8 + k*32..+8 per k-slice; identical for A and B ->
// D = A.B^T with row(t) = (lane>>4)*4 + j, col(s) = lane&15.
__global__ __launch_bounds__(256, 2) void maxsim_kernel(
    const float* __restrict__ anchor, const float* __restrict__ pos,
    const float* __restrict__ neg, float* __restrict__ scores,
    int* __restrict__ counter, float* __restrict__ out) {
  __shared__ float sInvA[64];
  __shared__ float sPart[4][64];

  int bs = blockIdx.x;      // 0..511 = batch*2 + side
  int b = bs >> 1;
  int side = bs & 1;
  const float* base = (side ? neg : pos) + (size_t)b * 512 * 128;
  const float* abase = anchor + (size_t)b * 64 * 128;

  int tid = threadIdx.x;
  int lane = tid & 63;
  int wid = tid >> 6;  // 0..3
  int r = lane & 15;   // fragment row within subtile / accumulator col
  int g = lane >> 4;   // k-group (elements g*8 + k*32)

  const float* sbase = base + (size_t)wid * 128 * 128;

#define ISSUE(dst, ci)                                                      \
  do {                                                                      \
    const float* p_ = sbase + (size_t)((ci) * 16 + r) * 128 + g * 8;        \
    _Pragma("unroll") for (int k_ = 0; k_ < 4; ++k_) {                      \
      dst[2 * k_] = *reinterpret_cast<const float4*>(p_ + k_ * 32);         \
      dst[2 * k_ + 1] = *reinterpret_cast<const float4*>(p_ + k_ * 32 + 4); \
    }                                                                       \
  } while (0)

  // Depth-2 prologue: chunks 0 and 1 in flight before/during the anchor phase.
  float4 buf0[8], buf1[8], buf2[8];  // 3-buffer rotation, static indexing
  ISSUE(buf0, 0);
  ISSUE(buf1, 1);

  // --- A: all 4 t-subtiles into registers, norms in-register. ---
  short8 aF[4][4];
#pragma unroll
  for (int tst = 0; tst < 4; ++tst) {
    const float* arow = abase + (size_t)(tst * 16 + r) * 128 + g * 8;
    float ssa[4];
#pragma unroll
    for (int k = 0; k < 4; ++k) {
      float4 v0 = *reinterpret_cast<const float4*>(arow + k * 32);
      float4 v1 = *reinterpret_cast<const float4*>(arow + k * 32 + 4);
      ssa[k] = sq4(v0) + sq4(v1);
      aF[tst][k] = pack8(v0, v1);
    }
    float ss = (ssa[0] + ssa[1]) + (ssa[2] + ssa[3]);  // tree, short chain
    ss += __shfl_xor(ss, 16);
    ss += __shfl_xor(ss, 32);
    if (g == 0) sInvA[tst * 16 + r] = 1.0f / fmaxf(sqrtf(ss), 1e-12f);
  }
  __syncthreads();  // sInvA ready; last sync until epilogue

  float rmax[4][4];
#pragma unroll
  for (int tst = 0; tst < 4; ++tst)
#pragma unroll
    for (int j = 0; j < 4; ++j) rmax[tst][j] = -1e30f;

  // Process chunk from `cur`, issuing chunk ci2 two ahead into the same
  // buffer slot being retired... (3-slot rotation: process slot i%3, issue
  // into slot (i+2)%3). WAR on the retiring slot is handled by the compiler
  // (new loads wait for last read of those VGPRs).
#define STEP(cur, nxt2, ci2, doissue)                                       \
  do {                                                                      \
    if (doissue) ISSUE(nxt2, ci2);                                          \
    float ss_ = ((sq4(cur[0]) + sq4(cur[1])) + (sq4(cur[2]) + sq4(cur[3]))) + \
                ((sq4(cur[4]) + sq4(cur[5])) + (sq4(cur[6]) + sq4(cur[7]))); \
    ss_ += __shfl_xor(ss_, 16);                                             \
    ss_ += __shfl_xor(ss_, 32);                                             \
    float invb_ = 1.0f / fmaxf(sqrtf(ss_), 1e-12f);                         \
    short8 bF_[4];                                                          \
    _Pragma("unroll") for (int k_ = 0; k_ < 4; ++k_) bF_[k_] =              \
        pack8(cur[2 * k_], cur[2 * k_ + 1]);                                \
    floatx4 acc_[4] = {{0.f, 0.f, 0.f, 0.f},                                \
                       {0.f, 0.f, 0.f, 0.f},                                \
                       {0.f, 0.f, 0.f, 0.f},                                \
                       {0.f, 0.f, 0.f, 0.f}};                               \
    _Pragma("unroll") for (int k_ = 0; k_ < 4; ++k_)                        \
        _Pragma("unroll") for (int t_ = 0; t_ < 4; ++t_) acc_[t_] =         \
            __builtin_amdgcn_mfma_f32_16x16x32_bf16(aF[t_][k_], bF_[k_],    \
                                                    acc_[t_], 0, 0, 0);     \
    _Pragma("unroll") for (int t_ = 0; t_ < 4; ++t_)                        \
        _Pragma("unroll") for (int j_ = 0; j_ < 4; ++j_) rmax[t_][j_] =     \
            fmaxf(rmax[t_][j_], acc_[t_][j_] * invb_);                      \
  } while (0)

  STEP(buf0, buf2, 2, 1);   // process c0, issue c2
  STEP(buf1, buf0, 3, 1);   // process c1, issue c3
  STEP(buf2, buf1, 4, 1);   // process c2, issue c4
  STEP(buf0, buf2, 5, 1);   // process c3, issue c5
  STEP(buf1, buf0, 6, 1);   // process c4, issue c6
  STEP(buf2, buf1, 7, 1);   // process c5, issue c7
  STEP(buf0, buf2, 0, 0);   // process c6
  STEP(buf1, buf2, 0, 0);   // process c7
#undef STEP
#undef ISSUE

  // Butterfly-max over cols (lane bits 0-3) -> per-t max over wave's s-range.
#pragma unroll
  for (int tst = 0; tst < 4; ++tst)
#pragma unroll
    for (int j = 0; j < 4; ++j) {
      float m = rmax[tst][j];
      m = fmaxf(m, __shfl_xor(m, 1));
      m = fmaxf(m, __shfl_xor(m, 2));
      m = fmaxf(m, __shfl_xor(m, 4));
      m = fmaxf(m, __shfl_xor(m, 8));
      rmax[tst][j] = m;  // t = tst*16 + g*4 + j, uniform over lane bits 0-3
    }
  if (r == 0) {
#pragma unroll
    for (int tst = 0; tst < 4; ++tst)
#pragma unroll
      for (int j = 0; j < 4; ++j)
        sPart[wid][tst * 16 + g * 4 + j] = rmax[tst][j];
  }
  __syncthreads();

  // Epilogue (wave 0): block score; last block computes hinge + mean inline.
  if (tid < 64) {
    float m = fmaxf(fmaxf(sPart[0][tid], sPart[1][tid]),
                    fmaxf(sPart[2][tid], sPart[3][tid]));
    float val = m * sInvA[tid];
#pragma unroll
    for (int mm = 1; mm < 64; mm <<= 1) val += __shfl_xor(val, mm);
    int lastflag = 0;
    if (tid == 0) {
      __hip_atomic_store(&scores[bs], val * (1.0f / 64.0f), __ATOMIC_RELEASE,
                         __HIP_MEMORY_SCOPE_AGENT);
      int prev = __hip_atomic_fetch_add(counter, 1, __ATOMIC_ACQ_REL,
                                        __HIP_MEMORY_SCOPE_AGENT);
      lastflag = (prev == 511);
    }
    lastflag = __shfl(lastflag, 0);
    if (lastflag) {
      // All 512 scores visible via the acq_rel counter chain. 4 batches/lane.
      float hsum = 0.f;
#pragma unroll
      for (int q = 0; q < 4; ++q) {
        int bb = tid * 4 + q;  // 0..255
        float p = __hip_atomic_load(&scores[2 * bb], __ATOMIC_RELAXED,
                                    __HIP_MEMORY_SCOPE_AGENT);
        float n = __hip_atomic_load(&scores[2 * bb + 1], __ATOMIC_RELAXED,
                                    __HIP_MEMORY_SCOPE_AGENT);
        hsum += fmaxf(MARGIN_F + n - p, 0.0f);
      }
#pragma unroll
      for (int mm = 1; mm < 64; mm <<= 1) hsum += __shfl_xor(hsum, mm);
      if (tid == 0) out[0] = hsum * (1.0f / 256.0f);
    }
  }
}

extern "C" void kernel_launch(void* const* d_in, const int* in_sizes, int n_in,
                              void* d_out, int out_size, void* d_ws,
                              size_t ws_size, hipStream_t stream) {
  const float* anchor = (const float*)d_in[0];
  const float* pos = (const float*)d_in[1];
  const float* neg = (const float*)d_in[2];
  float* scores = (float*)d_ws;           // 512 floats
  int* counter = (int*)((char*)d_ws + 512 * sizeof(float));
  // Zero the arrival counter each launch (capture-safe async memset).
  hipMemsetAsync(counter, 0, sizeof(int), stream);
  maxsim_kernel<<<dim3(512), dim3(256), 0, stream>>>(anchor, pos, neg, scores,
                                                     counter, (float*)d_out);
}